// Round 11
// baseline (2959.745 us; speedup 1.0000x reference)
//
#include <hip/hip_runtime.h>
#include <cstdint>
#include <cstddef>

// SO3NeuralCDE: B=16384, S=64, C=9, H=128, BN=64.
// RK4 over 63 knot intervals; field = 4-layer MLP (elu,elu,elu,tanh) contracted with dX.
// dt cancels: K_i = f(.) * (x[k+1]-x[k]).  t input unused.
//
// Precision: split fp16 (X = Xh + Xl) on every GEMM input; each logical MFMA =
// 3 MFMAs (Ah*Bh + Al*Bh + Ah*Bl), fp32 accumulate -> ~fp32-precision GEMMs.
//
// Round-10 analysis: 43% idle traced to serial MFMA3 chains (3 MFMAs into one
// acc; G1 = 12-deep serial, only 4 chains/SIMD vs ~6 needed at ~30cyc dep
// latency). Round 11: SPLIT ACCUMULATORS - each of the 3 split-precision terms
// gets its own accumulator chain (sum folded into the activation epilogue).
// Chain depth /3, chains/SIMD x3. No structural change vs round 10.

typedef _Float16 f16;
typedef _Float16 f16x8 __attribute__((ext_vector_type(8)));
typedef float f32x4 __attribute__((ext_vector_type(4)));

#define LOG2E     1.44269504088896340736f
#define TWOLOG2E  2.88539008177792681472f

#define MFMA(d, a, b, c) d = __builtin_amdgcn_mfma_f32_16x16x32_f16(a, b, c, 0, 0, 0)

// ws layout in f16 elements (hi at [0,90112), lo at [90112,180224)):
//   [0,8192)      W1P  (K=128,N=64)   frag idx ((nt*4+kb)*64+l)*8+j
//   [8192,12288)  W2P  (K=64,N=64)    ((nt*2+kb)*64+l)*8+j
//   [12288,16384) W3P  (K=64,N=64)
//   [16384,90112) W4P  per c: (K=64,N=128 cols 9h+c)  (((c*8+nt)*2+kb)*64+l)*8+j
__global__ void pack_weights(const float* __restrict__ W1, const float* __restrict__ W2,
                             const float* __restrict__ W3, const float* __restrict__ W4,
                             f16* __restrict__ wp)
{
  int t = blockIdx.x * 256 + threadIdx.x;
  if (t >= 90112) return;
  float v;
  if (t < 8192) {
    int j = t & 7, lr = (t >> 3) & 63, kb = (t >> 9) & 3, nt = t >> 11;
    int k = 32*kb + 8*(lr >> 4) + j, n = 16*nt + (lr & 15);
    v = W1[k*64 + n];
  } else if (t < 12288) {
    int u = t - 8192;
    int j = u & 7, lr = (u >> 3) & 63, kb = (u >> 9) & 1, nt = u >> 10;
    int k = 32*kb + 8*(lr >> 4) + j, n = 16*nt + (lr & 15);
    v = W2[k*64 + n];
  } else if (t < 16384) {
    int u = t - 12288;
    int j = u & 7, lr = (u >> 3) & 63, kb = (u >> 9) & 1, nt = u >> 10;
    int k = 32*kb + 8*(lr >> 4) + j, n = 16*nt + (lr & 15);
    v = W3[k*64 + n];
  } else {
    int u = t - 16384;
    int j = u & 7, lr = (u >> 3) & 63, kb = (u >> 9) & 1, nt = (u >> 10) & 7, c = u >> 13;
    int k = 32*kb + 8*(lr >> 4) + j, h = 16*nt + (lr & 15);
    v = W4[k*1152 + 9*h + c];
  }
  f16 hi = (f16)v;
  wp[t] = hi;
  wp[90112 + t] = (f16)(v - (float)hi);
}

// LDS map (137984 B):
//   s_hi[64][128]f16 @0      (16K, rowstride 256B, XOR-swizzled)   s_lo @16384
//   hA_hi[64][64]f16 @32768  (8K,  rowstride 128B, swizzled)       hA_lo @40960
//   hB_hi @49152                                                    hB_lo @57344
//   u_t[9][64]f32 @65536 (2304 B)
//   W123 hi @67840 (32768 B, packed frag order = ws elements [0,16384))
//   W123 lo @100608 (32768 B)
//   b4s[9][128]f32 @133376 (4608 B)  b4s[c*128+h] = b4[9h+c]*2log2e
// G1: s->hA (h1); G2: hA->hB (h2); G3: hB->hA (h3); G4: hA.
// Final epilogue reuses [0,32768) as z32[64][128]f32 and @49152 for Wo.
__global__ __launch_bounds__(512, 2) void cde_main(
    const float* __restrict__ x, const f16* __restrict__ wp,
    const float* __restrict__ b1, const float* __restrict__ b2,
    const float* __restrict__ b3, const float* __restrict__ b4,
    const float* __restrict__ Wi, const float* __restrict__ bi,
    const float* __restrict__ Wo, const float* __restrict__ bo,
    float* __restrict__ out)
{
  constexpr int SH = 0, SL = 16384, HAH = 32768, HAL = 40960, HBH = 49152, HBL = 57344;
  constexpr int UT = 65536, WH = 67840, WL = 100608, B4S = 133376;
  __shared__ __attribute__((aligned(16))) char smem[137984];

  const int tid = threadIdx.x;
  const int w   = tid >> 6;          // wave 0..7
  const int l   = tid & 63;
  const int l15 = l & 15, l4 = l >> 4;
  const int mh  = w >> 2, nq = w & 3;        // roles for G1-G3 (M-half, N-quarter)
  const int b0  = blockIdx.x << 6;           // batch tile base
  const int colG4 = (w << 4) + l15;          // this wave's h-column in G4/state
  const int xorv  = (l15 & 7) << 4;          // A-frag read swizzle (row = ..+l15)

  const f16x8* wpv = reinterpret_cast<const f16x8*>(wp);
  const f16x8* wlv = wpv + 11264;            // lo half (90112/8)

  const float b1v = b1[(nq<<4) + l15], b2v = b2[(nq<<4) + l15], b3v = b3[(nq<<4) + l15];
  const float b1x = b1v * LOG2E, b2x = b2v * LOG2E, b3x = b3v * LOG2E;

  const f32x4 zero4 = {0.f, 0.f, 0.f, 0.f};

  // ---------------- stage W1-3 frags (hi+lo) + b4s into LDS; init z0 inputs ----------------
  {
    const f32x4* wp4 = reinterpret_cast<const f32x4*>(wp);
    for (int idx = tid; idx < 2048; idx += 512) {
      ((f32x4*)(smem + WH))[idx] = wp4[idx];            // ws bytes [0,32768)
      ((f32x4*)(smem + WL))[idx] = wp4[11264 + idx];    // ws bytes [180224,212992)
    }
  }
  for (int idx = tid; idx < 1152; idx += 512) {
    int h = idx / 9, c = idx - h*9;                     // coalesced read of b4
    ((float*)(smem + B4S))[c*128 + h] = b4[idx] * TWOLOG2E;
  }
  for (int idx = tid; idx < 1152; idx += 512) ((float*)(smem + HAH))[idx] = Wi[idx];
  for (int idx = tid; idx <  128; idx += 512) ((float*)(smem + HBH))[idx] = bi[idx];
  for (int idx = tid; idx <  576; idx += 512) {
    int row = idx / 9, c = idx - row*9;                 // coalesced read of x0
    ((float*)(smem + UT))[c*64 + row] = x[(size_t)(b0 + row)*576 + c];
  }
  __syncthreads();

  f32x4 z[4], ark[4];
  {
    float wiv[9];
#pragma unroll
    for (int c = 0; c < 9; c++) wiv[c] = ((const float*)(smem + HAH))[c*128 + colG4];
    float biv = ((const float*)(smem + HBH))[colG4];
#pragma unroll
    for (int mi = 0; mi < 4; mi++) {
      f32x4 zz = {biv, biv, biv, biv};
#pragma unroll
      for (int c = 0; c < 9; c++) {
        f32x4 xv = *reinterpret_cast<const f32x4*>(smem + UT + c*256 + mi*64 + 16*l4);
#pragma unroll
        for (int r = 0; r < 4; r++) zz[r] = __builtin_fmaf(xv[r], wiv[c], zz[r]);
      }
      z[mi] = zz;
#pragma unroll
      for (int r = 0; r < 4; r++) {           // seed s with z0 (split hi/lo)
        int row  = 16*mi + 4*l4 + r;
        int byte = row*256 + ((colG4*2) ^ ((row & 7) << 4));
        f16 hi = (f16)zz[r];
        *reinterpret_cast<f16*>(smem + SH + byte) = hi;
        *reinterpret_cast<f16*>(smem + SL + byte) = (f16)(zz[r] - (float)hi);
      }
    }
  }

  // ---------------- time loop ----------------
#pragma unroll 1
  for (int k = 0; k < 63; ++k) {
#pragma unroll 1
    for (int st = 0; st < 4; ++st) {
      __syncthreads();                         // s (and prior u_t use) settled

      if (st == 0) {                           // u_t[c][row] = x[k+1]-x[k], coalesced
        for (int idx = tid; idx < 576; idx += 512) {
          int row = idx / 9, c = idx - row*9;
          const float* p = x + (size_t)(b0 + row)*576 + (size_t)k*9 + c;
          ((float*)(smem + UT))[c*64 + row] = p[9] - p[0];
        }
      }

      // ---- G1: s(64x128) @ W1 -> h1 (hA); 3-way split accumulators ----
      {
        f32x4 aA[2], aB[2], aC[2];
        aA[0] = aA[1] = aB[0] = aB[1] = aC[0] = aC[1] = zero4;
#pragma unroll
        for (int kb = 0; kb < 4; kb++) {
          int wb = ((nq*4 + kb)*64 + l)*16;
          f16x8 bh = *reinterpret_cast<const f16x8*>(smem + WH + wb);
          f16x8 bl = *reinterpret_cast<const f16x8*>(smem + WL + wb);
#pragma unroll
          for (int mi = 0; mi < 2; mi++) {
            int row = 32*mh + 16*mi + l15;
            int off = row*256 + ((16*l4 + 64*kb) ^ xorv);
            f16x8 ah = *reinterpret_cast<const f16x8*>(smem + SH + off);
            f16x8 al = *reinterpret_cast<const f16x8*>(smem + SL + off);
            MFMA(aA[mi], ah, bh, aA[mi]);
            MFMA(aB[mi], al, bh, aB[mi]);
            MFMA(aC[mi], ah, bl, aC[mi]);
          }
        }
#pragma unroll
        for (int mi = 0; mi < 2; mi++)
#pragma unroll
          for (int r = 0; r < 4; r++) {
            float pre = aA[mi][r] + aB[mi][r] + aC[mi][r];
            float lin = pre + b1v;
            float e   = __builtin_amdgcn_exp2f(__builtin_fmaf(pre, LOG2E, b1x)) - 1.0f;
            float res = lin > 0.0f ? lin : e;
            int row  = 32*mh + 16*mi + 4*l4 + r;
            int byte = row*128 + ((((nq<<4) + l15)*2) ^ ((row & 7) << 4));
            f16 hi = (f16)res;
            *reinterpret_cast<f16*>(smem + HAH + byte) = hi;
            *reinterpret_cast<f16*>(smem + HAL + byte) = (f16)(res - (float)hi);
          }
      }
      __syncthreads();

      // ---- G2: h1(hA) @ W2 -> h2 (hB); 3-way split accumulators ----
      {
        f32x4 aA[2], aB[2], aC[2];
        aA[0] = aA[1] = aB[0] = aB[1] = aC[0] = aC[1] = zero4;
#pragma unroll
        for (int kb = 0; kb < 2; kb++) {
          int wb = (1024 + (nq*2 + kb)*64 + l)*16;
          f16x8 bh = *reinterpret_cast<const f16x8*>(smem + WH + wb);
          f16x8 bl = *reinterpret_cast<const f16x8*>(smem + WL + wb);
#pragma unroll
          for (int mi = 0; mi < 2; mi++) {
            int row = 32*mh + 16*mi + l15;
            int off = row*128 + ((16*l4 + 64*kb) ^ xorv);
            f16x8 ah = *reinterpret_cast<const f16x8*>(smem + HAH + off);
            f16x8 al = *reinterpret_cast<const f16x8*>(smem + HAL + off);
            MFMA(aA[mi], ah, bh, aA[mi]);
            MFMA(aB[mi], al, bh, aB[mi]);
            MFMA(aC[mi], ah, bl, aC[mi]);
          }
        }
#pragma unroll
        for (int mi = 0; mi < 2; mi++)
#pragma unroll
          for (int r = 0; r < 4; r++) {
            float pre = aA[mi][r] + aB[mi][r] + aC[mi][r];
            float lin = pre + b2v;
            float e   = __builtin_amdgcn_exp2f(__builtin_fmaf(pre, LOG2E, b2x)) - 1.0f;
            float res = lin > 0.0f ? lin : e;
            int row  = 32*mh + 16*mi + 4*l4 + r;
            int byte = row*128 + ((((nq<<4) + l15)*2) ^ ((row & 7) << 4));
            f16 hi = (f16)res;
            *reinterpret_cast<f16*>(smem + HBH + byte) = hi;
            *reinterpret_cast<f16*>(smem + HBL + byte) = (f16)(res - (float)hi);
          }
      }
      __syncthreads();

      // ---- G3: h2(hB) @ W3 -> h3 (hA, reuse); 3-way split accumulators ----
      {
        f32x4 aA[2], aB[2], aC[2];
        aA[0] = aA[1] = aB[0] = aB[1] = aC[0] = aC[1] = zero4;
#pragma unroll
        for (int kb = 0; kb < 2; kb++) {
          int wb = (1536 + (nq*2 + kb)*64 + l)*16;
          f16x8 bh = *reinterpret_cast<const f16x8*>(smem + WH + wb);
          f16x8 bl = *reinterpret_cast<const f16x8*>(smem + WL + wb);
#pragma unroll
          for (int mi = 0; mi < 2; mi++) {
            int row = 32*mh + 16*mi + l15;
            int off = row*128 + ((16*l4 + 64*kb) ^ xorv);
            f16x8 ah = *reinterpret_cast<const f16x8*>(smem + HBH + off);
            f16x8 al = *reinterpret_cast<const f16x8*>(smem + HBL + off);
            MFMA(aA[mi], ah, bh, aA[mi]);
            MFMA(aB[mi], al, bh, aB[mi]);
            MFMA(aC[mi], ah, bl, aC[mi]);
          }
        }
#pragma unroll
        for (int mi = 0; mi < 2; mi++)
#pragma unroll
          for (int r = 0; r < 4; r++) {
            float pre = aA[mi][r] + aB[mi][r] + aC[mi][r];
            float lin = pre + b3v;
            float e   = __builtin_amdgcn_exp2f(__builtin_fmaf(pre, LOG2E, b3x)) - 1.0f;
            float res = lin > 0.0f ? lin : e;
            int row  = 32*mh + 16*mi + 4*l4 + r;
            int byte = row*128 + ((((nq<<4) + l15)*2) ^ ((row & 7) << 4));
            f16 hi = (f16)res;
            *reinterpret_cast<f16*>(smem + HAH + byte) = hi;
            *reinterpret_cast<f16*>(smem + HAL + byte) = (f16)(res - (float)hi);
          }
      }
      __syncthreads();

      // ---- G4: 9 channel-GEMMs (h3 @ W4_c), tanh, contract with u, RK4 ----
      // ROLLED c-loop + 1-deep W4 prefetch; 3-way split accumulators per (c,mi).
      {
        f16x8 a4h[4][2], a4l[4][2];
#pragma unroll
        for (int mi = 0; mi < 4; mi++)
#pragma unroll
          for (int kb = 0; kb < 2; kb++) {
            int row = 16*mi + l15;
            int off = row*128 + ((16*l4 + 64*kb) ^ xorv);
            a4h[mi][kb] = *reinterpret_cast<const f16x8*>(smem + HAH + off);
            a4l[mi][kb] = *reinterpret_cast<const f16x8*>(smem + HAL + off);
          }
        f32x4 K4[4];
#pragma unroll
        for (int mi = 0; mi < 4; mi++) K4[mi] = zero4;

        int ib = 2048 + (w*2)*64 + l;                  // c = 0 fragments
        f16x8 cbh0 = wpv[ib], cbl0 = wlv[ib], cbh1 = wpv[ib + 64], cbl1 = wlv[ib + 64];
#pragma unroll 1
        for (int c = 0; c < 9; c++) {
          f16x8 bh0 = cbh0, bl0 = cbl0, bh1 = cbh1, bl1 = cbl1;
          if (c < 8) {                                 // prefetch c+1 (wave-uniform branch)
            int jb = 2048 + (((c + 1)*8 + w)*2)*64 + l;
            cbh0 = wpv[jb]; cbl0 = wlv[jb]; cbh1 = wpv[jb + 64]; cbl1 = wlv[jb + 64];
          }
          f32x4 aA[4], aB[4], aC[4];
#pragma unroll
          for (int mi = 0; mi < 4; mi++) {
            MFMA(aA[mi], a4h[mi][0], bh0, zero4);
            MFMA(aA[mi], a4h[mi][1], bh1, aA[mi]);
            MFMA(aB[mi], a4l[mi][0], bh0, zero4);
            MFMA(aB[mi], a4l[mi][1], bh1, aB[mi]);
            MFMA(aC[mi], a4h[mi][0], bl0, zero4);
            MFMA(aC[mi], a4h[mi][1], bl1, aC[mi]);
          }
          float b4c = ((const float*)(smem + B4S))[c*128 + colG4];
#pragma unroll
          for (int mi = 0; mi < 4; mi++) {
            f32x4 uv = *reinterpret_cast<const f32x4*>(smem + UT + c*256 + mi*64 + 16*l4);
#pragma unroll
            for (int r = 0; r < 4; r++) {
              // tanh(pre + b4) = 1 - 2/(exp2((pre+b4)*2log2e)+1)  (inf-safe)
              float pre = aA[mi][r] + aB[mi][r] + aC[mi][r];
              float tex = __builtin_amdgcn_exp2f(__builtin_fmaf(pre, TWOLOG2E, b4c));
              float th  = __builtin_fmaf(__builtin_amdgcn_rcpf(tex + 1.0f), -2.0f, 1.0f);
              K4[mi][r] = __builtin_fmaf(th, uv[r], K4[mi][r]);
            }
          }
        }
        // RK4 combine (K = h*k): ark=K1+2K2+2K3; z += (ark+K4)/6
        if (st == 0) {
#pragma unroll
          for (int mi = 0; mi < 4; mi++) ark[mi] = K4[mi];
        } else if (st == 3) {
#pragma unroll
          for (int mi = 0; mi < 4; mi++)
#pragma unroll
            for (int r = 0; r < 4; r++)
              z[mi][r] = __builtin_fmaf(ark[mi][r] + K4[mi][r], 0.166666666667f, z[mi][r]);
        } else {
#pragma unroll
          for (int mi = 0; mi < 4; mi++)
#pragma unroll
            for (int r = 0; r < 4; r++)
              ark[mi][r] = __builtin_fmaf(2.0f, K4[mi][r], ark[mi][r]);
        }
        const float alpha = (st == 2) ? 1.0f : 0.5f;
#pragma unroll
        for (int mi = 0; mi < 4; mi++)
#pragma unroll
          for (int r = 0; r < 4; r++) {
            float sv = (st == 3) ? z[mi][r] : __builtin_fmaf(alpha, K4[mi][r], z[mi][r]);
            int row  = 16*mi + 4*l4 + r;
            int byte = row*256 + ((colG4*2) ^ ((row & 7) << 4));
            f16 hi = (f16)sv;
            *reinterpret_cast<f16*>(smem + SH + byte) = hi;
            *reinterpret_cast<f16*>(smem + SL + byte) = (f16)(sv - (float)hi);
          }
      }
    }
  }

  // ---------------- out = z @ Wo + bo ----------------
  __syncthreads();
#pragma unroll
  for (int mi = 0; mi < 4; mi++)
#pragma unroll
    for (int r = 0; r < 4; r++) {
      int row = 16*mi + 4*l4 + r;
      ((float*)smem)[row*128 + colG4] = z[mi][r];        // z32[64][128] @0
    }
  for (int idx = tid; idx < 1152; idx += 512) ((float*)(smem + HBH))[idx] = Wo[idx];
  __syncthreads();
  for (int idx = tid; idx < 576; idx += 512) {
    int b_ = idx / 9, c = idx - b_*9;
    float acc = bo[c];
#pragma unroll 4
    for (int h = 0; h < 128; h++)
      acc = __builtin_fmaf(((const float*)smem)[b_*128 + h],
                           ((const float*)(smem + HBH))[h*9 + c], acc);
    out[(size_t)(b0 + b_)*9 + c] = acc;
  }
}

extern "C" void kernel_launch(void* const* d_in, const int* in_sizes, int n_in,
                              void* d_out, int out_size, void* d_ws, size_t ws_size,
                              hipStream_t stream)
{
  // setup_inputs order: t, x, W1, b1, W2, b2, W3, b3, W4, b4, Wi, bi, Wo, bo
  const float* x  = (const float*)d_in[1];
  const float* W1 = (const float*)d_in[2];
  const float* b1 = (const float*)d_in[3];
  const float* W2 = (const float*)d_in[4];
  const float* b2 = (const float*)d_in[5];
  const float* W3 = (const float*)d_in[6];
  const float* b3 = (const float*)d_in[7];
  const float* W4 = (const float*)d_in[8];
  const float* b4 = (const float*)d_in[9];
  const float* Wi = (const float*)d_in[10];
  const float* bi = (const float*)d_in[11];
  const float* Wo = (const float*)d_in[12];
  const float* bo = (const float*)d_in[13];
  f16* wp = (f16*)d_ws;                       // 180224 f16 = 360448 B (hi + lo)

  pack_weights<<<352, 256, 0, stream>>>(W1, W2, W3, W4, wp);
  cde_main<<<256, 512, 0, stream>>>(x, wp, b1, b2, b3, b4, Wi, bi, Wo, bo, (float*)d_out);
}

// Round 12
// 2735.139 us; speedup vs baseline: 1.0821x; 1.0821x over previous
//
#include <hip/hip_runtime.h>
#include <cstdint>
#include <cstddef>

// SO3NeuralCDE: B=16384, S=64, C=9, H=128, BN=64.
// RK4 over 63 knot intervals; field = 4-layer MLP (elu,elu,elu,tanh) contracted with dX.
// dt cancels: K_i = f(.) * (x[k+1]-x[k]).  t input unused.
//
// Precision: split fp16 (X = Xh + Xl) on every GEMM input; each logical MFMA =
// 3 MFMAs (Ah*Bh + Al*Bh + Ah*Bl), fp32 accumulate -> ~fp32-precision GEMMs.
//
// FINAL STRUCTURE (session optimum, round 10 = 2737 us):
//   256 blocks x 512 thr, 64-row batch tile, 1 block/CU; W123 hi+lo in LDS;
//   W4 streamed from L2 (1x coverage, rolled c-loop, 1-deep named prefetch);
//   u_t staged under the st==0 barrier; 16 barriers/k.
// Verdict from rounds 5-11: combined MFMA+VALU issue ~90% busy, FETCH/WRITE ~0,
// occupancy raises all lose to the {LDS, VGPR, L2-stream} trilemma, MFMA count
// fixed by precision (3x split), VALU fixed by 73728 tanh/block-stage (2 transc
// each, accuracy >= 1e-6 required). This is the practical roofline.

typedef _Float16 f16;
typedef _Float16 f16x8 __attribute__((ext_vector_type(8)));
typedef float f32x4 __attribute__((ext_vector_type(4)));

#define LOG2E     1.44269504088896340736f
#define TWOLOG2E  2.88539008177792681472f

#define MFMA3(acc, ah, al, bh, bl)                                        \
  acc = __builtin_amdgcn_mfma_f32_16x16x32_f16(ah, bh, acc, 0, 0, 0);     \
  acc = __builtin_amdgcn_mfma_f32_16x16x32_f16(al, bh, acc, 0, 0, 0);     \
  acc = __builtin_amdgcn_mfma_f32_16x16x32_f16(ah, bl, acc, 0, 0, 0);

// ws layout in f16 elements (hi at [0,90112), lo at [90112,180224)):
//   [0,8192)      W1P  (K=128,N=64)   frag idx ((nt*4+kb)*64+l)*8+j
//   [8192,12288)  W2P  (K=64,N=64)    ((nt*2+kb)*64+l)*8+j
//   [12288,16384) W3P  (K=64,N=64)
//   [16384,90112) W4P  per c: (K=64,N=128 cols 9h+c)  (((c*8+nt)*2+kb)*64+l)*8+j
__global__ void pack_weights(const float* __restrict__ W1, const float* __restrict__ W2,
                             const float* __restrict__ W3, const float* __restrict__ W4,
                             f16* __restrict__ wp)
{
  int t = blockIdx.x * 256 + threadIdx.x;
  if (t >= 90112) return;
  float v;
  if (t < 8192) {
    int j = t & 7, lr = (t >> 3) & 63, kb = (t >> 9) & 3, nt = t >> 11;
    int k = 32*kb + 8*(lr >> 4) + j, n = 16*nt + (lr & 15);
    v = W1[k*64 + n];
  } else if (t < 12288) {
    int u = t - 8192;
    int j = u & 7, lr = (u >> 3) & 63, kb = (u >> 9) & 1, nt = u >> 10;
    int k = 32*kb + 8*(lr >> 4) + j, n = 16*nt + (lr & 15);
    v = W2[k*64 + n];
  } else if (t < 16384) {
    int u = t - 12288;
    int j = u & 7, lr = (u >> 3) & 63, kb = (u >> 9) & 1, nt = u >> 10;
    int k = 32*kb + 8*(lr >> 4) + j, n = 16*nt + (lr & 15);
    v = W3[k*64 + n];
  } else {
    int u = t - 16384;
    int j = u & 7, lr = (u >> 3) & 63, kb = (u >> 9) & 1, nt = (u >> 10) & 7, c = u >> 13;
    int k = 32*kb + 8*(lr >> 4) + j, h = 16*nt + (lr & 15);
    v = W4[k*1152 + 9*h + c];
  }
  f16 hi = (f16)v;
  wp[t] = hi;
  wp[90112 + t] = (f16)(v - (float)hi);
}

// LDS map (137984 B):
//   s_hi[64][128]f16 @0      (16K, rowstride 256B, XOR-swizzled)   s_lo @16384
//   hA_hi[64][64]f16 @32768  (8K,  rowstride 128B, swizzled)       hA_lo @40960
//   hB_hi @49152                                                    hB_lo @57344
//   u_t[9][64]f32 @65536 (2304 B)
//   W123 hi @67840 (32768 B, packed frag order = ws elements [0,16384))
//   W123 lo @100608 (32768 B)
//   b4s[9][128]f32 @133376 (4608 B)  b4s[c*128+h] = b4[9h+c]*2log2e
// G1: s->hA (h1); G2: hA->hB (h2); G3: hB->hA (h3); G4: hA.
// Final epilogue reuses [0,32768) as z32[64][128]f32 and @49152 for Wo.
__global__ __launch_bounds__(512, 2) void cde_main(
    const float* __restrict__ x, const f16* __restrict__ wp,
    const float* __restrict__ b1, const float* __restrict__ b2,
    const float* __restrict__ b3, const float* __restrict__ b4,
    const float* __restrict__ Wi, const float* __restrict__ bi,
    const float* __restrict__ Wo, const float* __restrict__ bo,
    float* __restrict__ out)
{
  constexpr int SH = 0, SL = 16384, HAH = 32768, HAL = 40960, HBH = 49152, HBL = 57344;
  constexpr int UT = 65536, WH = 67840, WL = 100608, B4S = 133376;
  __shared__ __attribute__((aligned(16))) char smem[137984];

  const int tid = threadIdx.x;
  const int w   = tid >> 6;          // wave 0..7
  const int l   = tid & 63;
  const int l15 = l & 15, l4 = l >> 4;
  const int mh  = w >> 2, nq = w & 3;        // roles for G1-G3 (M-half, N-quarter)
  const int b0  = blockIdx.x << 6;           // batch tile base
  const int colG4 = (w << 4) + l15;          // this wave's h-column in G4/state
  const int xorv  = (l15 & 7) << 4;          // A-frag read swizzle (row = ..+l15)

  const f16x8* wpv = reinterpret_cast<const f16x8*>(wp);
  const f16x8* wlv = wpv + 11264;            // lo half (90112/8)

  const float b1v = b1[(nq<<4) + l15], b2v = b2[(nq<<4) + l15], b3v = b3[(nq<<4) + l15];
  const float b1x = b1v * LOG2E, b2x = b2v * LOG2E, b3x = b3v * LOG2E;

  const f32x4 zero4 = {0.f, 0.f, 0.f, 0.f};

  // ---------------- stage W1-3 frags (hi+lo) + b4s into LDS; init z0 inputs ----------------
  {
    const f32x4* wp4 = reinterpret_cast<const f32x4*>(wp);
    for (int idx = tid; idx < 2048; idx += 512) {
      ((f32x4*)(smem + WH))[idx] = wp4[idx];            // ws bytes [0,32768)
      ((f32x4*)(smem + WL))[idx] = wp4[11264 + idx];    // ws bytes [180224,212992)
    }
  }
  for (int idx = tid; idx < 1152; idx += 512) {
    int h = idx / 9, c = idx - h*9;                     // coalesced read of b4
    ((float*)(smem + B4S))[c*128 + h] = b4[idx] * TWOLOG2E;
  }
  for (int idx = tid; idx < 1152; idx += 512) ((float*)(smem + HAH))[idx] = Wi[idx];
  for (int idx = tid; idx <  128; idx += 512) ((float*)(smem + HBH))[idx] = bi[idx];
  for (int idx = tid; idx <  576; idx += 512) {
    int row = idx / 9, c = idx - row*9;                 // coalesced read of x0
    ((float*)(smem + UT))[c*64 + row] = x[(size_t)(b0 + row)*576 + c];
  }
  __syncthreads();

  f32x4 z[4], ark[4];
  {
    float wiv[9];
#pragma unroll
    for (int c = 0; c < 9; c++) wiv[c] = ((const float*)(smem + HAH))[c*128 + colG4];
    float biv = ((const float*)(smem + HBH))[colG4];
#pragma unroll
    for (int mi = 0; mi < 4; mi++) {
      f32x4 zz = {biv, biv, biv, biv};
#pragma unroll
      for (int c = 0; c < 9; c++) {
        f32x4 xv = *reinterpret_cast<const f32x4*>(smem + UT + c*256 + mi*64 + 16*l4);
#pragma unroll
        for (int r = 0; r < 4; r++) zz[r] = __builtin_fmaf(xv[r], wiv[c], zz[r]);
      }
      z[mi] = zz;
#pragma unroll
      for (int r = 0; r < 4; r++) {           // seed s with z0 (split hi/lo)
        int row  = 16*mi + 4*l4 + r;
        int byte = row*256 + ((colG4*2) ^ ((row & 7) << 4));
        f16 hi = (f16)zz[r];
        *reinterpret_cast<f16*>(smem + SH + byte) = hi;
        *reinterpret_cast<f16*>(smem + SL + byte) = (f16)(zz[r] - (float)hi);
      }
    }
  }

  // ---------------- time loop ----------------
#pragma unroll 1
  for (int k = 0; k < 63; ++k) {
#pragma unroll 1
    for (int st = 0; st < 4; ++st) {
      __syncthreads();                         // s (and prior u_t use) settled

      if (st == 0) {                           // u_t[c][row] = x[k+1]-x[k], coalesced
        for (int idx = tid; idx < 576; idx += 512) {
          int row = idx / 9, c = idx - row*9;
          const float* p = x + (size_t)(b0 + row)*576 + (size_t)k*9 + c;
          ((float*)(smem + UT))[c*64 + row] = p[9] - p[0];
        }
      }

      // ---- G1: s(64x128) @ W1 -> h1 (hA) ----
      {
        f32x4 acc[2];
        acc[0] = zero4; acc[1] = zero4;
#pragma unroll
        for (int kb = 0; kb < 4; kb++) {
          int wb = ((nq*4 + kb)*64 + l)*16;
          f16x8 bh = *reinterpret_cast<const f16x8*>(smem + WH + wb);
          f16x8 bl = *reinterpret_cast<const f16x8*>(smem + WL + wb);
#pragma unroll
          for (int mi = 0; mi < 2; mi++) {
            int row = 32*mh + 16*mi + l15;
            int off = row*256 + ((16*l4 + 64*kb) ^ xorv);
            f16x8 ah = *reinterpret_cast<const f16x8*>(smem + SH + off);
            f16x8 al = *reinterpret_cast<const f16x8*>(smem + SL + off);
            MFMA3(acc[mi], ah, al, bh, bl);
          }
        }
#pragma unroll
        for (int mi = 0; mi < 2; mi++)
#pragma unroll
          for (int r = 0; r < 4; r++) {
            float pre = acc[mi][r];
            float lin = pre + b1v;
            float e   = __builtin_amdgcn_exp2f(__builtin_fmaf(pre, LOG2E, b1x)) - 1.0f;
            float res = lin > 0.0f ? lin : e;
            int row  = 32*mh + 16*mi + 4*l4 + r;
            int byte = row*128 + ((((nq<<4) + l15)*2) ^ ((row & 7) << 4));
            f16 hi = (f16)res;
            *reinterpret_cast<f16*>(smem + HAH + byte) = hi;
            *reinterpret_cast<f16*>(smem + HAL + byte) = (f16)(res - (float)hi);
          }
      }
      __syncthreads();

      // ---- G2: h1(hA) @ W2 -> h2 (hB) ----
      {
        f32x4 acc[2];
        acc[0] = zero4; acc[1] = zero4;
#pragma unroll
        for (int kb = 0; kb < 2; kb++) {
          int wb = (1024 + (nq*2 + kb)*64 + l)*16;
          f16x8 bh = *reinterpret_cast<const f16x8*>(smem + WH + wb);
          f16x8 bl = *reinterpret_cast<const f16x8*>(smem + WL + wb);
#pragma unroll
          for (int mi = 0; mi < 2; mi++) {
            int row = 32*mh + 16*mi + l15;
            int off = row*128 + ((16*l4 + 64*kb) ^ xorv);
            f16x8 ah = *reinterpret_cast<const f16x8*>(smem + HAH + off);
            f16x8 al = *reinterpret_cast<const f16x8*>(smem + HAL + off);
            MFMA3(acc[mi], ah, al, bh, bl);
          }
        }
#pragma unroll
        for (int mi = 0; mi < 2; mi++)
#pragma unroll
          for (int r = 0; r < 4; r++) {
            float pre = acc[mi][r];
            float lin = pre + b2v;
            float e   = __builtin_amdgcn_exp2f(__builtin_fmaf(pre, LOG2E, b2x)) - 1.0f;
            float res = lin > 0.0f ? lin : e;
            int row  = 32*mh + 16*mi + 4*l4 + r;
            int byte = row*128 + ((((nq<<4) + l15)*2) ^ ((row & 7) << 4));
            f16 hi = (f16)res;
            *reinterpret_cast<f16*>(smem + HBH + byte) = hi;
            *reinterpret_cast<f16*>(smem + HBL + byte) = (f16)(res - (float)hi);
          }
      }
      __syncthreads();

      // ---- G3: h2(hB) @ W3 -> h3 (hA, reuse) ----
      {
        f32x4 acc[2];
        acc[0] = zero4; acc[1] = zero4;
#pragma unroll
        for (int kb = 0; kb < 2; kb++) {
          int wb = (1536 + (nq*2 + kb)*64 + l)*16;
          f16x8 bh = *reinterpret_cast<const f16x8*>(smem + WH + wb);
          f16x8 bl = *reinterpret_cast<const f16x8*>(smem + WL + wb);
#pragma unroll
          for (int mi = 0; mi < 2; mi++) {
            int row = 32*mh + 16*mi + l15;
            int off = row*128 + ((16*l4 + 64*kb) ^ xorv);
            f16x8 ah = *reinterpret_cast<const f16x8*>(smem + HBH + off);
            f16x8 al = *reinterpret_cast<const f16x8*>(smem + HBL + off);
            MFMA3(acc[mi], ah, al, bh, bl);
          }
        }
#pragma unroll
        for (int mi = 0; mi < 2; mi++)
#pragma unroll
          for (int r = 0; r < 4; r++) {
            float pre = acc[mi][r];
            float lin = pre + b3v;
            float e   = __builtin_amdgcn_exp2f(__builtin_fmaf(pre, LOG2E, b3x)) - 1.0f;
            float res = lin > 0.0f ? lin : e;
            int row  = 32*mh + 16*mi + 4*l4 + r;
            int byte = row*128 + ((((nq<<4) + l15)*2) ^ ((row & 7) << 4));
            f16 hi = (f16)res;
            *reinterpret_cast<f16*>(smem + HAH + byte) = hi;
            *reinterpret_cast<f16*>(smem + HAL + byte) = (f16)(res - (float)hi);
          }
      }
      __syncthreads();

      // ---- G4: 9 channel-GEMMs (h3 @ W4_c), tanh, contract with u, RK4 ----
      // ROLLED c-loop + 1-deep W4-fragment prefetch (32 VGPRs in flight).
      {
        f16x8 a4h[4][2], a4l[4][2];
#pragma unroll
        for (int mi = 0; mi < 4; mi++)
#pragma unroll
          for (int kb = 0; kb < 2; kb++) {
            int row = 16*mi + l15;
            int off = row*128 + ((16*l4 + 64*kb) ^ xorv);
            a4h[mi][kb] = *reinterpret_cast<const f16x8*>(smem + HAH + off);
            a4l[mi][kb] = *reinterpret_cast<const f16x8*>(smem + HAL + off);
          }
        f32x4 K4[4];
#pragma unroll
        for (int mi = 0; mi < 4; mi++) K4[mi] = zero4;

        int ib = 2048 + (w*2)*64 + l;                  // c = 0 fragments
        f16x8 cbh0 = wpv[ib], cbl0 = wlv[ib], cbh1 = wpv[ib + 64], cbl1 = wlv[ib + 64];
#pragma unroll 1
        for (int c = 0; c < 9; c++) {
          f16x8 bh0 = cbh0, bl0 = cbl0, bh1 = cbh1, bl1 = cbl1;
          if (c < 8) {                                 // prefetch c+1 (wave-uniform branch)
            int jb = 2048 + (((c + 1)*8 + w)*2)*64 + l;
            cbh0 = wpv[jb]; cbl0 = wlv[jb]; cbh1 = wpv[jb + 64]; cbl1 = wlv[jb + 64];
          }
          f32x4 ac[4];
#pragma unroll
          for (int mi = 0; mi < 4; mi++) {
            ac[mi] = zero4;
            MFMA3(ac[mi], a4h[mi][0], a4l[mi][0], bh0, bl0);
            MFMA3(ac[mi], a4h[mi][1], a4l[mi][1], bh1, bl1);
          }
          float b4c = ((const float*)(smem + B4S))[c*128 + colG4];
#pragma unroll
          for (int mi = 0; mi < 4; mi++) {
            f32x4 uv = *reinterpret_cast<const f32x4*>(smem + UT + c*256 + mi*64 + 16*l4);
#pragma unroll
            for (int r = 0; r < 4; r++) {
              // tanh(pre + b4) = 1 - 2/(exp2((pre+b4)*2log2e)+1)  (inf-safe)
              float tex = __builtin_amdgcn_exp2f(__builtin_fmaf(ac[mi][r], TWOLOG2E, b4c));
              float th  = __builtin_fmaf(__builtin_amdgcn_rcpf(tex + 1.0f), -2.0f, 1.0f);
              K4[mi][r] = __builtin_fmaf(th, uv[r], K4[mi][r]);
            }
          }
        }
        // RK4 combine (K = h*k): ark=K1+2K2+2K3; z += (ark+K4)/6
        if (st == 0) {
#pragma unroll
          for (int mi = 0; mi < 4; mi++) ark[mi] = K4[mi];
        } else if (st == 3) {
#pragma unroll
          for (int mi = 0; mi < 4; mi++)
#pragma unroll
            for (int r = 0; r < 4; r++)
              z[mi][r] = __builtin_fmaf(ark[mi][r] + K4[mi][r], 0.166666666667f, z[mi][r]);
        } else {
#pragma unroll
          for (int mi = 0; mi < 4; mi++)
#pragma unroll
            for (int r = 0; r < 4; r++)
              ark[mi][r] = __builtin_fmaf(2.0f, K4[mi][r], ark[mi][r]);
        }
        const float alpha = (st == 2) ? 1.0f : 0.5f;
#pragma unroll
        for (int mi = 0; mi < 4; mi++)
#pragma unroll
          for (int r = 0; r < 4; r++) {
            float sv = (st == 3) ? z[mi][r] : __builtin_fmaf(alpha, K4[mi][r], z[mi][r]);
            int row  = 16*mi + 4*l4 + r;
            int byte = row*256 + ((colG4*2) ^ ((row & 7) << 4));
            f16 hi = (f16)sv;
            *reinterpret_cast<f16*>(smem + SH + byte) = hi;
            *reinterpret_cast<f16*>(smem + SL + byte) = (f16)(sv - (float)hi);
          }
      }
    }
  }

  // ---------------- out = z @ Wo + bo ----------------
  __syncthreads();
#pragma unroll
  for (int mi = 0; mi < 4; mi++)
#pragma unroll
    for (int r = 0; r < 4; r++) {
      int row = 16*mi + 4*l4 + r;
      ((float*)smem)[row*128 + colG4] = z[mi][r];        // z32[64][128] @0
    }
  for (int idx = tid; idx < 1152; idx += 512) ((float*)(smem + HBH))[idx] = Wo[idx];
  __syncthreads();
  for (int idx = tid; idx < 576; idx += 512) {
    int b_ = idx / 9, c = idx - b_*9;
    float acc = bo[c];
#pragma unroll 4
    for (int h = 0; h < 128; h++)
      acc = __builtin_fmaf(((const float*)smem)[b_*128 + h],
                           ((const float*)(smem + HBH))[h*9 + c], acc);
    out[(size_t)(b0 + b_)*9 + c] = acc;
  }
}

extern "C" void kernel_launch(void* const* d_in, const int* in_sizes, int n_in,
                              void* d_out, int out_size, void* d_ws, size_t ws_size,
                              hipStream_t stream)
{
  // setup_inputs order: t, x, W1, b1, W2, b2, W3, b3, W4, b4, Wi, bi, Wo, bo
  const float* x  = (const float*)d_in[1];
  const float* W1 = (const float*)d_in[2];
  const float* b1 = (const float*)d_in[3];
  const float* W2 = (const float*)d_in[4];
  const float* b2 = (const float*)d_in[5];
  const float* W3 = (const float*)d_in[6];
  const float* b3 = (const float*)d_in[7];
  const float* W4 = (const float*)d_in[8];
  const float* b4 = (const float*)d_in[9];
  const float* Wi = (const float*)d_in[10];
  const float* bi = (const float*)d_in[11];
  const float* Wo = (const float*)d_in[12];
  const float* bo = (const float*)d_in[13];
  f16* wp = (f16*)d_ws;                       // 180224 f16 = 360448 B (hi + lo)

  pack_weights<<<352, 256, 0, stream>>>(W1, W2, W3, W4, wp);
  cde_main<<<256, 512, 0, stream>>>(x, wp, b1, b2, b3, b4, Wi, bi, Wo, bo, (float*)d_out);
}